// Round 13
// baseline (2765.787 us; speedup 1.0000x reference)
//
#include <hip/hip_runtime.h>
#include <math.h>

#define NN 16384
#define SS 2048
#define TT 16
#define CHUNK 2048
#define UB 4

// np.tanh(f32) mimic: evaluate in f64, round once to f32 (~correctly rounded)
__device__ __forceinline__ float tanh_cr(float a) {
    return (float)tanh((double)a);
}

__device__ __forceinline__ float fold8(float a) {
    a += __shfl_xor(a, 4, 64);
    a += __shfl_xor(a, 1, 64);
    a += __shfl_xor(a, 2, 64);
    return a;
}

__device__ __forceinline__ float4 fma4(float4 w, float e, float4 a) {
    a.x = fmaf(w.x, e, a.x);
    a.y = fmaf(w.y, e, a.y);
    a.z = fmaf(w.z, e, a.z);
    a.w = fmaf(w.w, e, a.w);
    return a;
}

// inp[s,t] -> inpT[t,s], f32: tanh(where(u >= 0.01f, u, 0))
__global__ void prep_inp(const float* __restrict__ in, float* __restrict__ inpT) {
    int i = blockIdx.x * blockDim.x + threadIdx.x;
    if (i < SS * TT) {
        int s = i / TT, t = i % TT;
        float v = in[i];
        v = (v >= 0.01f) ? v : 0.0f;
        inpT[t * SS + s] = tanh_cr(v);
    }
}

__global__ void map_init(int* __restrict__ map) {
    int i = blockIdx.x * blockDim.x + threadIdx.x;
    if (i < NN) map[i] = -1;
}

__global__ void map_scatter(const int* __restrict__ idx, int* __restrict__ map) {
    int s = blockIdx.x * blockDim.x + threadIdx.x;
    if (s < SS) map[idx[s]] = s;
}

// t=0 (verified R6): 8 lanes/row, stripe j = k mod 8, fold(4,1,2).
__global__ __launch_bounds__(256) void step0(const float* __restrict__ W,
                                             const int* __restrict__ idx,
                                             const float* __restrict__ inp0,
                                             float* __restrict__ x_out,
                                             float* __restrict__ out) {
    int gid = blockIdx.x * blockDim.x + threadIdx.x;
    int row = gid >> 3;
    int j   = gid & 7;
    if (row >= NN) return;
    const float* __restrict__ wrow = W + (size_t)row * NN;
    float acc = 0.0f;
    #pragma unroll 16
    for (int k = j; k < SS; k += 8)
        acc = fmaf(wrow[idx[k]], inp0[k], acc);
    float y = fold8(acc);
    if (j == 0) {
        float v = (y >= 0.01f) ? y : 0.0f;
        v = tanh_cr(5.0f * v);
        x_out[row] = v;
        out[(size_t)row * TT + 0] = v;
    }
}

// ---------- fallback (verified R6 step_t) ----------
__global__ __launch_bounds__(256) void step_t(const float* __restrict__ W,
                                              const float* __restrict__ x_in,
                                              const float* __restrict__ inp_t,
                                              const int* __restrict__ map,
                                              float* __restrict__ x_out,
                                              float* __restrict__ out, int t) {
    int gid = blockIdx.x * blockDim.x + threadIdx.x;
    int row = gid >> 3;
    int j   = gid & 7;
    if (row >= NN) return;
    const float* __restrict__ wrow = W + (size_t)row * NN;
    float y = 0.0f;
    for (int c0 = 0; c0 < NN; c0 += CHUNK) {
        float acc = 0.0f;
        #pragma unroll 16
        for (int k = c0 + j; k < c0 + CHUNK; k += 8)
            acc = fmaf(wrow[k], x_in[k], acc);
        y += fold8(acc);
    }
    if (j == 0) {
        int m = map[row];
        if (m >= 0) y += inp_t[m];
        float v = (y >= 0.01f) ? y : 0.0f;
        v = tanh_cr(5.0f * v);
        x_out[row] = v;
        out[(size_t)row * TT + t] = v;
    }
}

// ---------- fast path ----------

// Wt[k][r] = W[r][k]. (verified R11)
__global__ __launch_bounds__(256) void transposeW(const float* __restrict__ W,
                                                  float* __restrict__ Wt) {
    __shared__ float lds[256][65];
    int b  = blockIdx.x;
    int k0 = (b & 255) << 6;
    int r0 = (b >> 8) << 8;
    int t  = threadIdx.x;
    #pragma unroll
    for (int it = 0; it < 16; ++it) {
        int idx = (it << 8) + t;
        int r = idx >> 4, q = idx & 15;
        float4 v = *reinterpret_cast<const float4*>(
            W + (size_t)(r0 + r) * NN + k0 + (q << 2));
        lds[r][(q << 2) + 0] = v.x;
        lds[r][(q << 2) + 1] = v.y;
        lds[r][(q << 2) + 2] = v.z;
        lds[r][(q << 2) + 3] = v.w;
    }
    __syncthreads();
    #pragma unroll
    for (int it = 0; it < 16; ++it) {
        int idx = (it << 8) + t;
        int kl = idx >> 6, q = idx & 63;
        float4 v;
        v.x = lds[(q << 2) + 0][kl];
        v.y = lds[(q << 2) + 1][kl];
        v.z = lds[(q << 2) + 2][kl];
        v.w = lds[(q << 2) + 3][kl];
        *reinterpret_cast<float4*>(
            Wt + (size_t)(k0 + kl) * NN + r0 + (q << 2)) = v;
    }
}

// Fused step: (a) combine prev csum -> x for chunk c (+out write by writer
// block), (b) order-preserving stripe compaction + zero-pad to npad,
// (c) 4-stream lockstep sparse axpy, 4 rows/lane (1KB segments/instr).
// Blocks: 256 = 8 chunks x 32 row-pair-groups. 4 waves = (rowhalf, stripehalf).
__global__ __launch_bounds__(256) void axpy_fused(const float* __restrict__ Wt,
                                                  const float* __restrict__ x0,
                                                  const float* __restrict__ csum_prev,
                                                  float* __restrict__ csum_out,
                                                  const float* __restrict__ inp_prev,
                                                  const int* __restrict__ map,
                                                  float* __restrict__ out, int t) {
    __shared__ float xl[2048];
    __shared__ float2 kl[8][256];
    __shared__ int n_lds[8];
    __shared__ int wcnt[4];
    __shared__ int npad_s;
    __shared__ float4 xch[2][64];      // u0 exchange per row-half (256 rows x f32)
    const int b = blockIdx.x, tid = threadIdx.x;
    const int c = b >> 5;
    const int lane = tid & 63, w = tid >> 6;

    // (a) x for chunk c
    if (t == 1) {
        for (int i = tid; i < 2048; i += 256) xl[i] = x0[(c << 11) + i];
    } else {
        const bool writer = (b & 31) == 0;
        #pragma unroll
        for (int i = 0; i < 8; ++i) {
            int row = (c << 11) + (i << 8) + tid;
            float y = csum_prev[row];
            #pragma unroll
            for (int cc = 1; cc < 8; ++cc) y += csum_prev[(size_t)cc * NN + row];
            int m = map[row];
            if (m >= 0) y += inp_prev[m];
            float v = (y >= 0.01f) ? y : 0.0f;
            v = tanh_cr(5.0f * v);
            xl[(i << 8) + tid] = v;
            if (writer) out[((size_t)row << 4) + (t - 1)] = v;
        }
    }
    __syncthreads();

    // (b) order-preserving compaction into 8 stripe lists
    for (int s = 0; s < 8; ++s) {
        float val = xl[(tid << 3) + s];          // k_local = 8*tid + s
        bool nz = (val != 0.0f);
        unsigned long long mask = __ballot(nz);
        int wp = __popcll(mask & (((unsigned long long)1 << lane) - 1ull));
        int wc = __popcll(mask);
        if (lane == 0) wcnt[w] = wc;
        __syncthreads();
        int off = 0;
        #pragma unroll
        for (int ww = 0; ww < 4; ++ww) if (ww < w) off += wcnt[ww];
        if (nz) kl[s][off + wp] =
            make_float2(__int_as_float((c << 11) + (tid << 3) + s), val);
        if (tid == 0) n_lds[s] = wcnt[0] + wcnt[1] + wcnt[2] + wcnt[3];
        __syncthreads();
    }
    // pad all lists to block-uniform npad with (k = chunk base, val = +0.0f):
    // fmaf(w, +0, acc) == acc bitwise for the real-entry chains (x>0).
    if (tid == 0) {
        int m = n_lds[0];
        #pragma unroll
        for (int s = 1; s < 8; ++s) m = max(m, n_lds[s]);
        npad_s = min((m + UB - 1) / UB * UB, 256);
    }
    __syncthreads();
    {
        const int npad = npad_s;
        int s = tid >> 5;
        const float2 padv = make_float2(__int_as_float(c << 11), 0.0f);
        for (int slot = n_lds[s] + (tid & 31); slot < npad; slot += 32)
            kl[s][slot] = padv;
    }
    __syncthreads();

    // (c) 4-stream lockstep axpy. Wave sh=0: stripes {0,4,1,5} -> u0;
    // sh=1: {2,6,3,7} -> u1. csum = u0 + u1 (frozen fold tree).
    const int rh = w >> 1, sh = w & 1;
    const int r0 = ((b & 31) << 9) + (rh << 8) + (lane << 2);   // 4 rows/lane
    const float* __restrict__ wb = Wt + r0;
    const int sA = sh << 1;            // 0 or 2
    const int npad = npad_s;

    float4 A0 = make_float4(0.f, 0.f, 0.f, 0.f);   // stripe sA
    float4 A1 = A0;                                 // stripe sA+4
    float4 A2 = A0;                                 // stripe sA+1
    float4 A3 = A0;                                 // stripe sA+5
    for (int j = 0; j < npad; j += UB) {
        float2 e0[UB], e1[UB], e2[UB], e3[UB];
        float4 w0[UB], w1[UB], w2[UB], w3[UB];
        #pragma unroll
        for (int u = 0; u < UB; ++u) {
            e0[u] = kl[sA][j + u];
            e1[u] = kl[sA + 4][j + u];
            e2[u] = kl[sA + 1][j + u];
            e3[u] = kl[sA + 5][j + u];
        }
        #pragma unroll
        for (int u = 0; u < UB; ++u) {
            w0[u] = *reinterpret_cast<const float4*>(wb + ((size_t)__float_as_int(e0[u].x) << 14));
            w1[u] = *reinterpret_cast<const float4*>(wb + ((size_t)__float_as_int(e1[u].x) << 14));
            w2[u] = *reinterpret_cast<const float4*>(wb + ((size_t)__float_as_int(e2[u].x) << 14));
            w3[u] = *reinterpret_cast<const float4*>(wb + ((size_t)__float_as_int(e3[u].x) << 14));
        }
        #pragma unroll
        for (int u = 0; u < UB; ++u) {        // ascending k within each stripe
            A0 = fma4(w0[u], e0[u].y, A0);
            A1 = fma4(w1[u], e1[u].y, A1);
            A2 = fma4(w2[u], e2[u].y, A2);
            A3 = fma4(w3[u], e3[u].y, A3);
        }
    }
    // b_s = a_s + a_{s+4}; u = b_sA + b_{sA+1}
    float4 bb0 = make_float4(A0.x + A1.x, A0.y + A1.y, A0.z + A1.z, A0.w + A1.w);
    float4 bb1 = make_float4(A2.x + A3.x, A2.y + A3.y, A2.z + A3.z, A2.w + A3.w);
    float4 uu  = make_float4(bb0.x + bb1.x, bb0.y + bb1.y, bb0.z + bb1.z, bb0.w + bb1.w);
    if (sh == 0) xch[rh][lane] = uu;
    __syncthreads();
    if (sh == 1) {
        float4 u0 = xch[rh][lane];
        float4 cs = make_float4(u0.x + uu.x, u0.y + uu.y, u0.z + uu.z, u0.w + uu.w);
        *reinterpret_cast<float4*>(csum_out + (size_t)c * NN + r0) = cs;
    }
}

// final combine for t=15.
__global__ __launch_bounds__(256) void combine_final(const float* __restrict__ csum,
                                                     const float* __restrict__ inp_t,
                                                     const int* __restrict__ map,
                                                     float* __restrict__ out) {
    int row = blockIdx.x * 256 + threadIdx.x;
    float y = csum[row];
    #pragma unroll
    for (int cc = 1; cc < 8; ++cc) y += csum[(size_t)cc * NN + row];
    int m = map[row];
    if (m >= 0) y += inp_t[m];
    float v = (y >= 0.01f) ? y : 0.0f;
    v = tanh_cr(5.0f * v);
    out[((size_t)row << 4) + (TT - 1)] = v;
}

extern "C" void kernel_launch(void* const* d_in, const int* in_sizes, int n_in,
                              void* d_out, int out_size, void* d_ws, size_t ws_size,
                              hipStream_t stream) {
    const float* W    = (const float*)d_in[0];
    const float* intt = (const float*)d_in[1];
    const int*   idx  = (const int*)d_in[2];
    float* out = (float*)d_out;

    char* ws = (char*)d_ws;
    float* inpT = (float*)(ws + 0);              // 131072 B
    int*   map  = (int*)(ws + 131072);           // 65536 B
    float* xa   = (float*)(ws + 196608);         // 65536 B
    float* xb   = (float*)(ws + 262144);         // 65536 B (fallback only)
    float* cs0  = (float*)(ws + 327680);         // 524288 B
    float* cs1  = (float*)(ws + 851968);         // 524288 B
    float* Wt   = (float*)(ws + 1376256);        // 1 GiB
    const size_t NEED = 1376256ull + (size_t)NN * NN * 4ull;

    prep_inp<<<(SS * TT + 255) / 256, 256, 0, stream>>>(intt, inpT);
    map_init<<<NN / 256, 256, 0, stream>>>(map);
    map_scatter<<<SS / 256, 256, 0, stream>>>(idx, map);
    step0<<<NN * 8 / 256, 256, 0, stream>>>(W, idx, inpT, xa, out);

    if (ws_size >= NEED) {
        transposeW<<<256 * 64, 256, 0, stream>>>(W, Wt);
        for (int t = 1; t < TT; ++t) {
            const float* csp = ((t - 1) & 1) ? cs1 : cs0;
            float*       cso = (t & 1) ? cs1 : cs0;
            axpy_fused<<<256, 256, 0, stream>>>(Wt, xa, csp, cso,
                                                inpT + (size_t)(t - 1) * SS,
                                                map, out, t);
        }
        combine_final<<<NN / 256, 256, 0, stream>>>(cs1, inpT + (size_t)(TT - 1) * SS,
                                                    map, out);
    } else {
        float* xi_ = xa;
        float* xo_ = xb;
        for (int t = 1; t < TT; ++t) {
            step_t<<<NN * 8 / 256, 256, 0, stream>>>(W, xi_, inpT + (size_t)t * SS,
                                                     map, xo_, out, t);
            float* tmp = xi_; xi_ = xo_; xo_ = tmp;
        }
    }
}

// Round 15
// 2364.779 us; speedup vs baseline: 1.1696x; 1.1696x over previous
//
#include <hip/hip_runtime.h>
#include <math.h>

#define NN 16384
#define SS 2048
#define TT 16
#define CHUNK 2048
#define UB 16

typedef float vf4 __attribute__((ext_vector_type(4)));  // clang-native for nontemporal

// np.tanh(f32) mimic: evaluate in f64, round once to f32 (~correctly rounded)
__device__ __forceinline__ float tanh_cr(float a) {
    return (float)tanh((double)a);
}

__device__ __forceinline__ float fold8(float a) {
    a += __shfl_xor(a, 4, 64);
    a += __shfl_xor(a, 1, 64);
    a += __shfl_xor(a, 2, 64);
    return a;
}

// inp[s,t] -> inpT[t,s], f32: tanh(where(u >= 0.01f, u, 0))
__global__ void prep_inp(const float* __restrict__ in, float* __restrict__ inpT) {
    int i = blockIdx.x * blockDim.x + threadIdx.x;
    if (i < SS * TT) {
        int s = i / TT, t = i % TT;
        float v = in[i];
        v = (v >= 0.01f) ? v : 0.0f;
        inpT[t * SS + s] = tanh_cr(v);
    }
}

__global__ void map_init(int* __restrict__ map) {
    int i = blockIdx.x * blockDim.x + threadIdx.x;
    if (i < NN) map[i] = -1;
}

__global__ void map_scatter(const int* __restrict__ idx, int* __restrict__ map) {
    int s = blockIdx.x * blockDim.x + threadIdx.x;
    if (s < SS) map[idx[s]] = s;
}

// t=0 (verified R6): 8 lanes/row, stripe j = k mod 8, fold(4,1,2).
__global__ __launch_bounds__(256) void step0(const float* __restrict__ W,
                                             const int* __restrict__ idx,
                                             const float* __restrict__ inp0,
                                             float* __restrict__ x_out,
                                             float* __restrict__ out) {
    int gid = blockIdx.x * blockDim.x + threadIdx.x;
    int row = gid >> 3;
    int j   = gid & 7;
    if (row >= NN) return;
    const float* __restrict__ wrow = W + (size_t)row * NN;
    float acc = 0.0f;
    #pragma unroll 16
    for (int k = j; k < SS; k += 8)
        acc = fmaf(wrow[idx[k]], inp0[k], acc);
    float y = fold8(acc);
    if (j == 0) {
        float v = (y >= 0.01f) ? y : 0.0f;
        v = tanh_cr(5.0f * v);
        x_out[row] = v;
        out[(size_t)row * TT + 0] = v;
    }
}

// ---------- fallback (verified R6 step_t) ----------
__global__ __launch_bounds__(256) void step_t(const float* __restrict__ W,
                                              const float* __restrict__ x_in,
                                              const float* __restrict__ inp_t,
                                              const int* __restrict__ map,
                                              float* __restrict__ x_out,
                                              float* __restrict__ out, int t) {
    int gid = blockIdx.x * blockDim.x + threadIdx.x;
    int row = gid >> 3;
    int j   = gid & 7;
    if (row >= NN) return;
    const float* __restrict__ wrow = W + (size_t)row * NN;
    float y = 0.0f;
    for (int c0 = 0; c0 < NN; c0 += CHUNK) {
        float acc = 0.0f;
        #pragma unroll 16
        for (int k = c0 + j; k < c0 + CHUNK; k += 8)
            acc = fmaf(wrow[k], x_in[k], acc);
        y += fold8(acc);
    }
    if (j == 0) {
        int m = map[row];
        if (m >= 0) y += inp_t[m];
        float v = (y >= 0.01f) ? y : 0.0f;
        v = tanh_cr(5.0f * v);
        x_out[row] = v;
        out[(size_t)row * TT + t] = v;
    }
}

// ---------- fast path ----------

// Wt[k][r] = W[r][k]. 128x128 tile, 512B segments both directions,
// 2 blocks/CU (67.6KB LDS), nontemporal streaming (no reuse).
__global__ __launch_bounds__(256) void transposeW(const float* __restrict__ W,
                                                  float* __restrict__ Wt) {
    __shared__ float lds[128][132];
    int b  = blockIdx.x;
    int k0 = (b & 127) << 7;
    int r0 = (b >> 7) << 7;
    int t  = threadIdx.x;
    #pragma unroll
    for (int it = 0; it < 16; ++it) {
        int idx = (it << 8) + t;           // 0..4095
        int r = idx >> 5, q = idx & 31;    // 32 float4 per row
        vf4 v = __builtin_nontemporal_load(
            reinterpret_cast<const vf4*>(W + (size_t)(r0 + r) * NN + k0 + (q << 2)));
        *reinterpret_cast<vf4*>(&lds[r][q << 2]) = v;   // row base 528B, 16B aligned
    }
    __syncthreads();
    #pragma unroll
    for (int it = 0; it < 16; ++it) {
        int idx = (it << 8) + t;
        int k = idx >> 5, q = idx & 31;
        vf4 v;
        v.x = lds[(q << 2) + 0][k];
        v.y = lds[(q << 2) + 1][k];
        v.z = lds[(q << 2) + 2][k];
        v.w = lds[(q << 2) + 3][k];
        __builtin_nontemporal_store(v,
            reinterpret_cast<vf4*>(Wt + (size_t)(k0 + k) * NN + r0 + (q << 2)));
    }
}

// One sequential fmaf chain over stripe s's nonzero k list (ascending k),
// scalar (this lane's single row). Bit-identical to the R6 stripe chain.
__device__ __forceinline__ float stripe_chain1(const float* __restrict__ wb,
                                               const float2 (*kl)[256],
                                               const int* n_lds, int s) {
    int n = n_lds[s];
    float p = 0.0f;
    int j = 0;
    for (; j + UB <= n; j += UB) {
        float2 es[UB];
        float  wv[UB];
        #pragma unroll
        for (int u = 0; u < UB; ++u) es[u] = kl[s][j + u];
        #pragma unroll
        for (int u = 0; u < UB; ++u)
            wv[u] = wb[(size_t)__float_as_int(es[u].x) << 14];
        #pragma unroll
        for (int u = 0; u < UB; ++u)          // ascending k: frozen order
            p = fmaf(wv[u], es[u].y, p);
    }
    for (; j < n; ++j) {
        float2 e = kl[s][j];
        p = fmaf(wb[(size_t)__float_as_int(e.x) << 14], e.y, p);
    }
    return p;
}

// Fused step: (a) combine prev csum -> x for chunk c (+out by writer block),
// (b) order-preserving stripe compaction, (c) scalar sparse axpy, 1 row/lane.
// 512 blocks = 8 chunks x 64 row-groups of 256 rows -> 2048 waves (2 blk/CU).
__global__ __launch_bounds__(256) void axpy_fused(const float* __restrict__ Wt,
                                                  const float* __restrict__ x0,
                                                  const float* __restrict__ csum_prev,
                                                  float* __restrict__ csum_out,
                                                  const float* __restrict__ inp_prev,
                                                  const int* __restrict__ map,
                                                  float* __restrict__ out, int t) {
    __shared__ float xl[2048];
    __shared__ float2 kl[8][256];
    __shared__ int n_lds[8];
    __shared__ int wcnt[4];
    const int b = blockIdx.x, tid = threadIdx.x;
    const int c = b >> 6;                 // chunk 0..7
    const int lane = tid & 63, w = tid >> 6;

    // (a) x for chunk c
    if (t == 1) {
        for (int i = tid; i < 2048; i += 256) xl[i] = x0[(c << 11) + i];
    } else {
        const bool writer = (b & 63) == 0;
        #pragma unroll
        for (int i = 0; i < 8; ++i) {
            int row = (c << 11) + (i << 8) + tid;
            float y = csum_prev[row];
            #pragma unroll
            for (int cc = 1; cc < 8; ++cc) y += csum_prev[(size_t)cc * NN + row];
            int m = map[row];
            if (m >= 0) y += inp_prev[m];
            float v = (y >= 0.01f) ? y : 0.0f;
            v = tanh_cr(5.0f * v);
            xl[(i << 8) + tid] = v;
            if (writer) out[((size_t)row << 4) + (t - 1)] = v;
        }
    }
    __syncthreads();

    // (b) order-preserving compaction into 8 stripe lists
    for (int s = 0; s < 8; ++s) {
        float val = xl[(tid << 3) + s];          // k_local = 8*tid + s
        bool nz = (val != 0.0f);
        unsigned long long mask = __ballot(nz);
        int wp = __popcll(mask & (((unsigned long long)1 << lane) - 1ull));
        int wc = __popcll(mask);
        if (lane == 0) wcnt[w] = wc;
        __syncthreads();
        int off = 0;
        #pragma unroll
        for (int ww = 0; ww < 4; ++ww) if (ww < w) off += wcnt[ww];
        if (nz) kl[s][off + wp] =
            make_float2(__int_as_float((c << 11) + (tid << 3) + s), val);
        if (tid == 0) n_lds[s] = wcnt[0] + wcnt[1] + wcnt[2] + wcnt[3];
        __syncthreads();
    }

    // (c) scalar sparse axpy; fold tree in-lane, frozen association:
    // csum = ((b0+b1)+(b2+b3)), b_s = a_s + a_{s+4}
    const int row = ((b & 63) << 8) + tid;       // this lane's row
    const float* __restrict__ wb = Wt + row;

    float b0 = stripe_chain1(wb, kl, n_lds, 0) + stripe_chain1(wb, kl, n_lds, 4);
    float b1 = stripe_chain1(wb, kl, n_lds, 1) + stripe_chain1(wb, kl, n_lds, 5);
    float b2 = stripe_chain1(wb, kl, n_lds, 2) + stripe_chain1(wb, kl, n_lds, 6);
    float b3 = stripe_chain1(wb, kl, n_lds, 3) + stripe_chain1(wb, kl, n_lds, 7);
    float cs = (b0 + b1) + (b2 + b3);
    csum_out[(size_t)c * NN + row] = cs;
}

// final combine for t=15.
__global__ __launch_bounds__(256) void combine_final(const float* __restrict__ csum,
                                                     const float* __restrict__ inp_t,
                                                     const int* __restrict__ map,
                                                     float* __restrict__ out) {
    int row = blockIdx.x * 256 + threadIdx.x;
    float y = csum[row];
    #pragma unroll
    for (int cc = 1; cc < 8; ++cc) y += csum[(size_t)cc * NN + row];
    int m = map[row];
    if (m >= 0) y += inp_t[m];
    float v = (y >= 0.01f) ? y : 0.0f;
    v = tanh_cr(5.0f * v);
    out[((size_t)row << 4) + (TT - 1)] = v;
}

extern "C" void kernel_launch(void* const* d_in, const int* in_sizes, int n_in,
                              void* d_out, int out_size, void* d_ws, size_t ws_size,
                              hipStream_t stream) {
    const float* W    = (const float*)d_in[0];
    const float* intt = (const float*)d_in[1];
    const int*   idx  = (const int*)d_in[2];
    float* out = (float*)d_out;

    char* ws = (char*)d_ws;
    float* inpT = (float*)(ws + 0);              // 131072 B
    int*   map  = (int*)(ws + 131072);           // 65536 B
    float* xa   = (float*)(ws + 196608);         // 65536 B
    float* xb   = (float*)(ws + 262144);         // 65536 B (fallback only)
    float* cs0  = (float*)(ws + 327680);         // 524288 B
    float* cs1  = (float*)(ws + 851968);         // 524288 B
    float* Wt   = (float*)(ws + 1376256);        // 1 GiB
    const size_t NEED = 1376256ull + (size_t)NN * NN * 4ull;

    prep_inp<<<(SS * TT + 255) / 256, 256, 0, stream>>>(intt, inpT);
    map_init<<<NN / 256, 256, 0, stream>>>(map);
    map_scatter<<<SS / 256, 256, 0, stream>>>(idx, map);
    step0<<<NN * 8 / 256, 256, 0, stream>>>(W, idx, inpT, xa, out);

    if (ws_size >= NEED) {
        transposeW<<<128 * 128, 256, 0, stream>>>(W, Wt);
        for (int t = 1; t < TT; ++t) {
            const float* csp = ((t - 1) & 1) ? cs1 : cs0;
            float*       cso = (t & 1) ? cs1 : cs0;
            axpy_fused<<<512, 256, 0, stream>>>(Wt, xa, csp, cso,
                                                inpT + (size_t)(t - 1) * SS,
                                                map, out, t);
        }
        combine_final<<<NN / 256, 256, 0, stream>>>(cs1, inpT + (size_t)(TT - 1) * SS,
                                                    map, out);
    } else {
        float* xi_ = xa;
        float* xo_ = xb;
        for (int t = 1; t < TT; ++t) {
            step_t<<<NN * 8 / 256, 256, 0, stream>>>(W, xi_, inpT + (size_t)t * SS,
                                                     map, xo_, out, t);
            float* tmp = xi_; xi_ = xo_; xo_ = tmp;
        }
    }
}

// Round 16
// 2036.795 us; speedup vs baseline: 1.3579x; 1.1610x over previous
//
#include <hip/hip_runtime.h>
#include <math.h>

#define NN 16384
#define SS 2048
#define TT 16
#define CHUNK 2048
#define UB 16

typedef float vf4 __attribute__((ext_vector_type(4)));  // clang-native for nontemporal

// np.tanh(f32) mimic: evaluate in f64, round once to f32 (~correctly rounded)
__device__ __forceinline__ float tanh_cr(float a) {
    return (float)tanh((double)a);
}

__device__ __forceinline__ float fold8(float a) {
    a += __shfl_xor(a, 4, 64);
    a += __shfl_xor(a, 1, 64);
    a += __shfl_xor(a, 2, 64);
    return a;
}

// inp[s,t] -> inpT[t,s], f32: tanh(where(u >= 0.01f, u, 0))
__global__ void prep_inp(const float* __restrict__ in, float* __restrict__ inpT) {
    int i = blockIdx.x * blockDim.x + threadIdx.x;
    if (i < SS * TT) {
        int s = i / TT, t = i % TT;
        float v = in[i];
        v = (v >= 0.01f) ? v : 0.0f;
        inpT[t * SS + s] = tanh_cr(v);
    }
}

__global__ void map_init(int* __restrict__ map) {
    int i = blockIdx.x * blockDim.x + threadIdx.x;
    if (i < NN) map[i] = -1;
}

__global__ void map_scatter(const int* __restrict__ idx, int* __restrict__ map) {
    int s = blockIdx.x * blockDim.x + threadIdx.x;
    if (s < SS) map[idx[s]] = s;
}

// t=0 (verified R6): 8 lanes/row, stripe j = k mod 8, fold(4,1,2).
__global__ __launch_bounds__(256) void step0(const float* __restrict__ W,
                                             const int* __restrict__ idx,
                                             const float* __restrict__ inp0,
                                             float* __restrict__ x_out,
                                             float* __restrict__ out) {
    int gid = blockIdx.x * blockDim.x + threadIdx.x;
    int row = gid >> 3;
    int j   = gid & 7;
    if (row >= NN) return;
    const float* __restrict__ wrow = W + (size_t)row * NN;
    float acc = 0.0f;
    #pragma unroll 16
    for (int k = j; k < SS; k += 8)
        acc = fmaf(wrow[idx[k]], inp0[k], acc);
    float y = fold8(acc);
    if (j == 0) {
        float v = (y >= 0.01f) ? y : 0.0f;
        v = tanh_cr(5.0f * v);
        x_out[row] = v;
        out[(size_t)row * TT + 0] = v;
    }
}

// ---------- fallback (verified R6 step_t) ----------
__global__ __launch_bounds__(256) void step_t(const float* __restrict__ W,
                                              const float* __restrict__ x_in,
                                              const float* __restrict__ inp_t,
                                              const int* __restrict__ map,
                                              float* __restrict__ x_out,
                                              float* __restrict__ out, int t) {
    int gid = blockIdx.x * blockDim.x + threadIdx.x;
    int row = gid >> 3;
    int j   = gid & 7;
    if (row >= NN) return;
    const float* __restrict__ wrow = W + (size_t)row * NN;
    float y = 0.0f;
    for (int c0 = 0; c0 < NN; c0 += CHUNK) {
        float acc = 0.0f;
        #pragma unroll 16
        for (int k = c0 + j; k < c0 + CHUNK; k += 8)
            acc = fmaf(wrow[k], x_in[k], acc);
        y += fold8(acc);
    }
    if (j == 0) {
        int m = map[row];
        if (m >= 0) y += inp_t[m];
        float v = (y >= 0.01f) ? y : 0.0f;
        v = tanh_cr(5.0f * v);
        x_out[row] = v;
        out[(size_t)row * TT + t] = v;
    }
}

// ---------- fast path ----------

// Wt[k][r] = W[r][k]. 128x128 tile, 512B segments both ways, NT streaming.
__global__ __launch_bounds__(256) void transposeW(const float* __restrict__ W,
                                                  float* __restrict__ Wt) {
    __shared__ float lds[128][132];
    int b  = blockIdx.x;
    int k0 = (b & 127) << 7;
    int r0 = (b >> 7) << 7;
    int t  = threadIdx.x;
    #pragma unroll
    for (int it = 0; it < 16; ++it) {
        int idx = (it << 8) + t;
        int r = idx >> 5, q = idx & 31;
        vf4 v = __builtin_nontemporal_load(
            reinterpret_cast<const vf4*>(W + (size_t)(r0 + r) * NN + k0 + (q << 2)));
        *reinterpret_cast<vf4*>(&lds[r][q << 2]) = v;
    }
    __syncthreads();
    #pragma unroll
    for (int it = 0; it < 16; ++it) {
        int idx = (it << 8) + t;
        int k = idx >> 5, q = idx & 31;
        vf4 v;
        v.x = lds[(q << 2) + 0][k];
        v.y = lds[(q << 2) + 1][k];
        v.z = lds[(q << 2) + 2][k];
        v.w = lds[(q << 2) + 3][k];
        __builtin_nontemporal_store(v,
            reinterpret_cast<vf4*>(Wt + (size_t)(k0 + k) * NN + r0 + (q << 2)));
    }
}

// One sequential fmaf chain over stripe s's nonzero k list (ascending k),
// scalar (this lane's single row), NT loads (each Wt byte read once/step).
__device__ __forceinline__ float stripe_chain1(const float* __restrict__ wb,
                                               const float2 (*kl)[256],
                                               const int* n_lds, int s) {
    int n = n_lds[s];
    float p = 0.0f;
    int j = 0;
    for (; j + UB <= n; j += UB) {
        float2 es[UB];
        float  wv[UB];
        #pragma unroll
        for (int u = 0; u < UB; ++u) es[u] = kl[s][j + u];
        #pragma unroll
        for (int u = 0; u < UB; ++u)
            wv[u] = __builtin_nontemporal_load(
                wb + ((size_t)__float_as_int(es[u].x) << 14));
        #pragma unroll
        for (int u = 0; u < UB; ++u)          // ascending k: frozen order
            p = fmaf(wv[u], es[u].y, p);
    }
    for (; j < n; ++j) {
        float2 e = kl[s][j];
        p = fmaf(__builtin_nontemporal_load(
                     wb + ((size_t)__float_as_int(e.x) << 14)), e.y, p);
    }
    return p;
}

// Fused step, stripe-half split: 1024 blocks = 8 chunks x 128 row-groups
// (128 rows). tid&127 = row_local, tid>>7 = sh. sh=0 computes u0=b0+b1
// (stripes 0,4,1,5), sh=1 computes u1=b2+b3 (stripes 2,6,3,7);
// cs = u0+u1 via LDS exchange — token-identical frozen fold tree.
__global__ __launch_bounds__(256) void axpy_fused(const float* __restrict__ Wt,
                                                  const float* __restrict__ x0,
                                                  const float* __restrict__ csum_prev,
                                                  float* __restrict__ csum_out,
                                                  const float* __restrict__ inp_prev,
                                                  const int* __restrict__ map,
                                                  float* __restrict__ out, int t) {
    __shared__ float xl[2048];
    __shared__ float2 kl[8][256];
    __shared__ int n_lds[8];
    __shared__ int wcnt[4];
    __shared__ float u_xch[128];
    const int b = blockIdx.x, tid = threadIdx.x;
    const int c = b >> 7;                 // chunk 0..7
    const int g = b & 127;                // row-group (128 rows)
    const int lane = tid & 63, w = tid >> 6;

    // (a) x for chunk c (recomputed per block; deterministic f32)
    if (t == 1) {
        for (int i = tid; i < 2048; i += 256) xl[i] = x0[(c << 11) + i];
    } else {
        const bool writer = (g == 0);
        #pragma unroll
        for (int i = 0; i < 8; ++i) {
            int row = (c << 11) + (i << 8) + tid;
            float y = csum_prev[row];
            #pragma unroll
            for (int cc = 1; cc < 8; ++cc) y += csum_prev[(size_t)cc * NN + row];
            int m = map[row];
            if (m >= 0) y += inp_prev[m];
            float v = (y >= 0.01f) ? y : 0.0f;
            v = tanh_cr(5.0f * v);
            xl[(i << 8) + tid] = v;
            if (writer) out[((size_t)row << 4) + (t - 1)] = v;
        }
    }
    __syncthreads();

    // (b) order-preserving compaction into 8 stripe lists
    for (int s = 0; s < 8; ++s) {
        float val = xl[(tid << 3) + s];          // k_local = 8*tid + s
        bool nz = (val != 0.0f);
        unsigned long long mask = __ballot(nz);
        int wp = __popcll(mask & (((unsigned long long)1 << lane) - 1ull));
        int wc = __popcll(mask);
        if (lane == 0) wcnt[w] = wc;
        __syncthreads();
        int off = 0;
        #pragma unroll
        for (int ww = 0; ww < 4; ++ww) if (ww < w) off += wcnt[ww];
        if (nz) kl[s][off + wp] =
            make_float2(__int_as_float((c << 11) + (tid << 3) + s), val);
        if (tid == 0) n_lds[s] = wcnt[0] + wcnt[1] + wcnt[2] + wcnt[3];
        __syncthreads();
    }

    // (c) half-split scalar sparse axpy
    const int rl  = tid & 127;
    const int sh  = tid >> 7;
    const int row = (g << 7) + rl;
    const float* __restrict__ wb = Wt + row;
    const int sA = sh << 1;                      // 0 (sh=0) or 2 (sh=1)

    float bf = stripe_chain1(wb, kl, n_lds, sA)     + stripe_chain1(wb, kl, n_lds, sA + 4);
    float bs = stripe_chain1(wb, kl, n_lds, sA + 1) + stripe_chain1(wb, kl, n_lds, sA + 5);
    float u = bf + bs;                           // u0 = b0+b1  |  u1 = b2+b3
    if (sh == 0) u_xch[rl] = u;
    __syncthreads();
    if (sh == 1)                                 // cs = (b0+b1)+(b2+b3)
        csum_out[(size_t)c * NN + row] = u_xch[rl] + u;
}

// final combine for t=15.
__global__ __launch_bounds__(256) void combine_final(const float* __restrict__ csum,
                                                     const float* __restrict__ inp_t,
                                                     const int* __restrict__ map,
                                                     float* __restrict__ out) {
    int row = blockIdx.x * 256 + threadIdx.x;
    float y = csum[row];
    #pragma unroll
    for (int cc = 1; cc < 8; ++cc) y += csum[(size_t)cc * NN + row];
    int m = map[row];
    if (m >= 0) y += inp_t[m];
    float v = (y >= 0.01f) ? y : 0.0f;
    v = tanh_cr(5.0f * v);
    out[((size_t)row << 4) + (TT - 1)] = v;
}

extern "C" void kernel_launch(void* const* d_in, const int* in_sizes, int n_in,
                              void* d_out, int out_size, void* d_ws, size_t ws_size,
                              hipStream_t stream) {
    const float* W    = (const float*)d_in[0];
    const float* intt = (const float*)d_in[1];
    const int*   idx  = (const int*)d_in[2];
    float* out = (float*)d_out;

    char* ws = (char*)d_ws;
    float* inpT = (float*)(ws + 0);              // 131072 B
    int*   map  = (int*)(ws + 131072);           // 65536 B
    float* xa   = (float*)(ws + 196608);         // 65536 B
    float* xb   = (float*)(ws + 262144);         // 65536 B (fallback only)
    float* cs0  = (float*)(ws + 327680);         // 524288 B
    float* cs1  = (float*)(ws + 851968);         // 524288 B
    float* Wt   = (float*)(ws + 1376256);        // 1 GiB
    const size_t NEED = 1376256ull + (size_t)NN * NN * 4ull;

    prep_inp<<<(SS * TT + 255) / 256, 256, 0, stream>>>(intt, inpT);
    map_init<<<NN / 256, 256, 0, stream>>>(map);
    map_scatter<<<SS / 256, 256, 0, stream>>>(idx, map);
    step0<<<NN * 8 / 256, 256, 0, stream>>>(W, idx, inpT, xa, out);

    if (ws_size >= NEED) {
        transposeW<<<128 * 128, 256, 0, stream>>>(W, Wt);
        for (int t = 1; t < TT; ++t) {
            const float* csp = ((t - 1) & 1) ? cs1 : cs0;
            float*       cso = (t & 1) ? cs1 : cs0;
            axpy_fused<<<1024, 256, 0, stream>>>(Wt, xa, csp, cso,
                                                 inpT + (size_t)(t - 1) * SS,
                                                 map, out, t);
        }
        combine_final<<<NN / 256, 256, 0, stream>>>(cs1, inpT + (size_t)(TT - 1) * SS,
                                                    map, out);
    } else {
        float* xi_ = xa;
        float* xo_ = xb;
        for (int t = 1; t < TT; ++t) {
            step_t<<<NN * 8 / 256, 256, 0, stream>>>(W, xi_, inpT + (size_t)t * SS,
                                                     map, xo_, out, t);
            float* tmp = xi_; xi_ = xo_; xo_ = tmp;
        }
    }
}